// Round 8
// baseline (1210.142 us; speedup 1.0000x reference)
//
#include <hip/hip_runtime.h>
#include <stdint.h>

#define CDIV(a,b) (((a)+(b)-1)/(b))

typedef unsigned short u16;
using bf16x8   = __attribute__((ext_vector_type(8))) short;
using floatx4  = __attribute__((ext_vector_type(4))) float;
using floatx16 = __attribute__((ext_vector_type(16))) float;

constexpr int B_N   = 2048;   // batch
constexpr int IN_N  = 784;
constexpr int H_N   = 512;
constexpr int OUT_N = 512;
constexpr int E_N   = 8;
constexpr int ER_N  = 4;      // recurrent experts
constexpr int ES_N  = 4;      // simple experts
constexpr int T_N   = 28;
constexpr int F_N   = 28;
constexpr int G4H   = 2048;   // 4*H
constexpr int KA    = 544;    // 512 (h) + 28 (x_t) + 4 pad
constexpr int KB8   = KA / 8; // 68 k8-blocks
constexpr int NKI   = KA / 16;// 34 mfma k-iters
constexpr int XP    = 800;    // 784 padded

__device__ __forceinline__ u16 f2bf(float f) {
  union { float f; uint32_t u; } v; v.f = f;
  uint32_t r = v.u + 0x7fffu + ((v.u >> 16) & 1u);   // RNE
  return (u16)(r >> 16);
}
__device__ __forceinline__ float sigm(float x)  { return 1.f / (1.f + __expf(-x)); }
__device__ __forceinline__ float tanhf_(float x){ return 1.f - 2.f / (__expf(2.f * x) + 1.f); }

__device__ __forceinline__ void async16(const void* g, void* l) {
  __builtin_amdgcn_global_load_lds(
      (__attribute__((address_space(1))) void*)g,
      (__attribute__((address_space(3))) void*)l, 16, 0, 0);
}

// ============ persistent weight-stationary LSTM, v5: group barriers ============
// 256 blocks x 512 threads (cooperative, 1 block/CU, 139 KB LDS).
// Block (z = blk>>6, nt = (blk>>2)&15, mr = blk&3) owns expert z,
// h-cols [32*nt,+32), batch rows [512*mr,+512).
// W slice (4 gate-tiles of 32 rows x KA) staged to LDS ONCE; c-state in VGPRs
// for all 28 steps. Per step: A-frag loads -> 34x8 MFMA -> fused cell epilogue
// -> h stores (ping-pong A-frag buffers) -> 16-block barrier over group (z,mr)
// (the only blocks whose h/x this block consumes). Monotonic counter barrier:
// release-add (device scope, flushes L2 to LLC) + relaxed spin + acquire fence
// (invalidates L1/L2). Correct regardless of block->XCD placement (G16).
__global__ __launch_bounds__(512, 2)
void lstm_persist(const u16* __restrict__ Wc, const float* __restrict__ brec,
                  const u16* __restrict__ xb, u16* __restrict__ A0,
                  u16* __restrict__ A1, u16* __restrict__ Hlast,
                  int* __restrict__ Gbar)
{
  extern __shared__ __align__(16) u16 Ws[];   // 4*KB8*256 u16 = 139264 B
  const int tid  = threadIdx.x;
  const int lane = tid & 63;
  const int wave = tid >> 6;
  const int blk  = blockIdx.x;
  const int z    = blk >> 6;
  const int nt   = (blk >> 2) & 15;
  const int mr   = blk & 3;
  const int ln   = lane & 31;
  const int hw   = lane >> 5;
  const int gslot = (z * 4 + mr) * 64;        // 256B-spaced counter per group

  // ---- stage resident W slice into LDS (once): 17 x 1KB async chunks/wave ----
  {
    const u16* Wsrc = Wc + (size_t)(z * 16 + nt) * (4 * KB8 * 256);
    const int base = wave * (17 * 512);        // u16 units
#pragma unroll
    for (int it = 0; it < 17; ++it)
      async16(Wsrc + base + it * 512 + lane * 8, Ws + base + it * 512);
  }

  float bb[4];
#pragma unroll
  for (int j = 0; j < 4; ++j)
    bb[j] = brec[((z * 16 + nt) * 4 + j) * 32 + ln];

  float c[2][16];
#pragma unroll
  for (int i = 0; i < 2; ++i)
#pragma unroll
    for (int r = 0; r < 16; ++r) c[i][r] = 0.f;

  const int mblk0 = mr * 16 + wave * 2;
  const int hcol  = nt * 32 + ln;
  const size_t zoff = (size_t)z * ((size_t)64 * KB8 * 256);
  __syncthreads();   // W resident

  for (int t = 0; t < T_N; ++t) {
    const u16* Az  = ((t & 1) ? A1 : A0) + zoff;
    u16*       Aoz = ((t & 1) ? A0 : A1) + zoff;

    const u16* Ap0 = Az + ((size_t)mblk0 * KB8 + hw) * 256 + ln * 8;
    const u16* Ap1 = Az + ((size_t)(mblk0 + 1) * KB8 + hw) * 256 + ln * 8;

    bf16x8 pa0[2], pa1[2];                     // depth-2 A prefetch ring
    pa0[0] = *(const bf16x8*)Ap0;          pa1[0] = *(const bf16x8*)Ap1;
    pa0[1] = *(const bf16x8*)(Ap0 + 512);  pa1[1] = *(const bf16x8*)(Ap1 + 512);

    floatx16 acc[2][4] = {};
#pragma unroll 2
    for (int kk = 0; kk < NKI; ++kk) {
      bf16x8 a0 = pa0[kk & 1], a1 = pa1[kk & 1];
      if (kk + 2 < NKI) {
        pa0[kk & 1] = *(const bf16x8*)(Ap0 + (size_t)(kk + 2) * 512);
        pa1[kk & 1] = *(const bf16x8*)(Ap1 + (size_t)(kk + 2) * 512);
      }
      const u16* Bp = Ws + (2 * kk + hw) * 256 + ln * 8;
      bf16x8 b0 = *(const bf16x8*)(Bp);
      bf16x8 b1 = *(const bf16x8*)(Bp + 1 * KB8 * 256);
      bf16x8 b2 = *(const bf16x8*)(Bp + 2 * KB8 * 256);
      bf16x8 b3 = *(const bf16x8*)(Bp + 3 * KB8 * 256);
      acc[0][0] = __builtin_amdgcn_mfma_f32_32x32x16_bf16(a0, b0, acc[0][0], 0, 0, 0);
      acc[0][1] = __builtin_amdgcn_mfma_f32_32x32x16_bf16(a0, b1, acc[0][1], 0, 0, 0);
      acc[0][2] = __builtin_amdgcn_mfma_f32_32x32x16_bf16(a0, b2, acc[0][2], 0, 0, 0);
      acc[0][3] = __builtin_amdgcn_mfma_f32_32x32x16_bf16(a0, b3, acc[0][3], 0, 0, 0);
      acc[1][0] = __builtin_amdgcn_mfma_f32_32x32x16_bf16(a1, b0, acc[1][0], 0, 0, 0);
      acc[1][1] = __builtin_amdgcn_mfma_f32_32x32x16_bf16(a1, b1, acc[1][1], 0, 0, 0);
      acc[1][2] = __builtin_amdgcn_mfma_f32_32x32x16_bf16(a1, b2, acc[1][2], 0, 0, 0);
      acc[1][3] = __builtin_amdgcn_mfma_f32_32x32x16_bf16(a1, b3, acc[1][3], 0, 0, 0);
    }

    // ---- cell epilogue: c in registers across steps ----
    const int last = (t == T_N - 1);
#pragma unroll
    for (int i = 0; i < 2; ++i) {
      const int mb = mblk0 + i;
#pragma unroll
      for (int r = 0; r < 16; ++r) {
        float pi = acc[i][0][r] + bb[0];
        float pf = acc[i][1][r] + bb[1];
        float pg = acc[i][2][r] + bb[2];
        float po = acc[i][3][r] + bb[3];
        float cv = sigm(pf) * c[i][r] + sigm(pi) * tanhf_(pg);
        c[i][r] = cv;
        u16 hb = f2bf(sigm(po) * tanhf_(cv));
        // 32x32 C/D layout: col=lane&31, row=(r&3)+8*(r>>2)+4*(lane>>5)
        int mrow = 4 * hw + (r & 3) + 8 * (r >> 2);
        if (!last)
          Aoz[((size_t)mb * KB8 + (hcol >> 3)) * 256 + mrow * 8 + (hcol & 7)] = hb;
        else
          Hlast[((size_t)(z * B_N + mb * 32 + mrow)) * H_N + hcol] = hb;
      }
    }

    // ---- stage x_{t+1} slice (k in [512,540)) into Aout: nt==0 blocks only ----
    if (nt == 0 && t + 1 < T_N) {
      for (int idx = tid; idx < 512 * F_N; idx += 512) {
        int ml  = idx / F_N, col = idx - ml * F_N;
        int m   = mr * 512 + ml;
        int k   = H_N + col;
        Aoz[((size_t)(m >> 5) * KB8 + (k >> 3)) * 256 + (m & 31) * 8 + (k & 7)] =
            xb[(size_t)m * XP + (t + 1) * F_N + col];
      }
    }

    // ---- 16-block group barrier (z,mr): monotonic counter ----
    if (t + 1 < T_N) {
      __syncthreads();   // drains vmcnt(0): all waves' h/x stores complete in L2
      if (tid == 0) {
        __hip_atomic_fetch_add(&Gbar[gslot], 1, __ATOMIC_RELEASE,
                               __HIP_MEMORY_SCOPE_AGENT);
        const int target = 16 * (t + 1);
        while (__hip_atomic_load(&Gbar[gslot], __ATOMIC_RELAXED,
                                 __HIP_MEMORY_SCOPE_AGENT) < target)
          __builtin_amdgcn_s_sleep(1);
        __builtin_amdgcn_fence(__ATOMIC_ACQUIRE, "agent");
      }
      __syncthreads();
    }
  }
}

// ============ generic GEMM (tail): C[z] = A[z] @ B[z]^T + bias[z] ============
template<int RELU, int OBF>
__global__ __launch_bounds__(256, 2)
void gemm_bt(const u16* __restrict__ A, int lda, long sAz,
             const u16* __restrict__ Bw, int ldb, long sBz,
             const float* __restrict__ bias, int sBiz,
             void* __restrict__ Cv, int ldc, long sCz,
             int K)
{
  __shared__ __align__(16) u16 As[128 * 32];
  __shared__ __align__(16) u16 Bs[128 * 32];
  const int tid  = threadIdx.x;
  const int lane = tid & 63;
  const int wave = tid >> 6;
  const int m0 = blockIdx.y * 128;
  const int n0 = blockIdx.x * 128;
  const int z  = blockIdx.z;
  const u16* Ab = A  + (size_t)z * sAz;
  const u16* Bb = Bw + (size_t)z * sBz;

  const int wm   = (wave & 1) * 64;
  const int wn   = (wave >> 1) * 64;
  const int lm   = lane & 15;
  const int quad = lane >> 4;

  const int s0 = wave * 64 + lane;
  const int r0 = s0 >> 2, c0 = (s0 & 3) * 8;
  const int s1 = s0 + 256;
  const int r1 = s1 >> 2, c1 = (s1 & 3) * 8;

  floatx4 acc[4][4] = {};

  for (int k0 = 0; k0 < K; k0 += 32) {
    async16(Ab + (size_t)(m0 + r0) * lda + (k0 + c0), As + wave * 512);
    async16(Ab + (size_t)(m0 + r1) * lda + (k0 + c1), As + 2048 + wave * 512);
    async16(Bb + (size_t)(n0 + r0) * ldb + (k0 + c0), Bs + wave * 512);
    async16(Bb + (size_t)(n0 + r1) * ldb + (k0 + c1), Bs + 2048 + wave * 512);
    __syncthreads();
    bf16x8 af[4], bf_[4];
#pragma unroll
    for (int i = 0; i < 4; ++i)
      af[i] = *(const bf16x8*)&As[(wm + i * 16 + lm) * 32 + quad * 8];
#pragma unroll
    for (int j = 0; j < 4; ++j)
      bf_[j] = *(const bf16x8*)&Bs[(wn + j * 16 + lm) * 32 + quad * 8];
#pragma unroll
    for (int i = 0; i < 4; ++i)
#pragma unroll
      for (int j = 0; j < 4; ++j)
        acc[i][j] = __builtin_amdgcn_mfma_f32_16x16x32_bf16(af[i], bf_[j], acc[i][j], 0, 0, 0);
    __syncthreads();
  }

  float bj[4];
#pragma unroll
  for (int j = 0; j < 4; ++j)
    bj[j] = bias ? bias[z * sBiz + n0 + wn + j * 16 + lm] : 0.f;

#pragma unroll
  for (int i = 0; i < 4; ++i) {
#pragma unroll
    for (int r = 0; r < 4; ++r) {
      int m = m0 + wm + i * 16 + quad * 4 + r;
      size_t row = (size_t)z * sCz + (size_t)m * ldc;
#pragma unroll
      for (int j = 0; j < 4; ++j) {
        int n = n0 + wn + j * 16 + lm;
        float v = acc[i][j][r] + bj[j];
        if (RELU) v = fmaxf(v, 0.f);
        if (OBF) ((u16*)Cv)[row + n] = f2bf(v);
        else     ((float*)Cv)[row + n] = v;
      }
    }
  }
}

// ============ gate: softmax(scores/e), top-5, renormalize. one wave per row ============
__global__ __launch_bounds__(256)
void gate_k(const float* __restrict__ x, const float* __restrict__ Wg,
            const float* __restrict__ bg, float* __restrict__ Wt)
{
  int lane = threadIdx.x & 63;
  int row  = blockIdx.x * 4 + (threadIdx.x >> 6);
  float ps[E_N];
#pragma unroll
  for (int e = 0; e < E_N; ++e) ps[e] = 0.f;
  const float* xr = x + (size_t)row * IN_N;
  for (int k = lane; k < IN_N; k += 64) {
    float xv = xr[k];
#pragma unroll
    for (int e = 0; e < E_N; ++e) ps[e] += xv * Wg[e * IN_N + k];
  }
#pragma unroll
  for (int e = 0; e < E_N; ++e) {
#pragma unroll
    for (int off = 32; off >= 1; off >>= 1) ps[e] += __shfl_down(ps[e], off);
  }
  if (lane == 0) {
    float s[E_N], mx = -1e30f;
#pragma unroll
    for (int e = 0; e < E_N; ++e) { s[e] = (ps[e] + bg[e]) * 0.36787944117144233f; mx = fmaxf(mx, s[e]); }
    float pr[E_N], sum = 0.f;
#pragma unroll
    for (int e = 0; e < E_N; ++e) { pr[e] = __expf(s[e] - mx); sum += pr[e]; }
    float inv = 1.f / sum;
#pragma unroll
    for (int e = 0; e < E_N; ++e) pr[e] *= inv;
    unsigned used = 0; float wsum = 0.f;
    for (int k = 0; k < 5; ++k) {
      int am = -1; float bv = -1.f;
      for (int e = 0; e < E_N; ++e)
        if (!((used >> e) & 1) && pr[e] > bv) { bv = pr[e]; am = e; }
      used |= 1u << am; wsum += pr[am];
    }
    float winv = 1.f / (wsum + 1e-8f);
    for (int e = 0; e < E_N; ++e)
      Wt[row * E_N + e] = ((used >> e) & 1) ? pr[e] * winv : 0.f;
  }
}

// ============ combine ============
__global__ __launch_bounds__(256)
void combine_k(const float* __restrict__ O, const float* __restrict__ Wt, float* __restrict__ out)
{
  int idx = blockIdx.x * 256 + threadIdx.x;
  if (idx >= B_N * OUT_N) return;
  int b = idx / OUT_N;
  float a = 0.f;
#pragma unroll
  for (int e = 0; e < E_N; ++e)
    a += Wt[b * E_N + e] * O[(size_t)e * B_N * OUT_N + idx];
  out[idx] = a;
}

// ============ prep kernels ============
__global__ void prep_x_k(const float* __restrict__ x, u16* __restrict__ xb) {
  int idx = blockIdx.x * 256 + threadIdx.x;
  if (idx >= B_N * XP) return;
  int k = idx % XP, b = idx / XP;
  xb[idx] = f2bf(k < IN_N ? x[(size_t)b * IN_N + k] : 0.f);
}
// W in B-frag layout: [z][nt][gate j 4][k8][ln 32][e8 8]; gate j holds h = 32*nt + ln
__global__ void prep_wfrag_k(const float* __restrict__ Whh, const float* __restrict__ Wih,
                             u16* __restrict__ Wc) {
  int idx = blockIdx.x * 256 + threadIdx.x;
  if (idx >= ER_N * G4H * KA) return;
  int e8 = idx & 7, ln = (idx >> 3) & 31;
  int k8 = (idx >> 8) % KB8;
  int rest = (idx >> 8) / KB8;
  int j = rest & 3, nt = (rest >> 2) & 15, z = rest >> 6;
  int h = nt * 32 + ln, k = k8 * 8 + e8;
  int g = j * H_N + h;
  float v = 0.f;
  if (k < H_N)            v = Whh[((size_t)(z * G4H + g)) * H_N + k];
  else if (k < H_N + F_N) v = Wih[((size_t)(z * G4H + g)) * F_N + (k - H_N)];
  Wc[idx] = f2bf(v);
}
__global__ void prep_bfrag_k(const float* __restrict__ bih, const float* __restrict__ bhh,
                             float* __restrict__ o) {
  int idx = blockIdx.x * 256 + threadIdx.x;
  if (idx >= ER_N * G4H) return;
  int ln = idx & 31, j = (idx >> 5) & 3, nt = (idx >> 7) & 15, z = idx >> 11;
  int g = z * G4H + j * H_N + nt * 32 + ln;
  o[idx] = bih[g] + bhh[g];
}
__global__ void cvt_k(const float* __restrict__ in, u16* __restrict__ o, int n) {
  int idx = blockIdx.x * 256 + threadIdx.x;
  if (idx < n) o[idx] = f2bf(in[idx]);
}
__global__ void prep_w1_k(const float* __restrict__ W1, u16* __restrict__ o) {
  int idx = blockIdx.x * 256 + threadIdx.x;
  if (idx >= ES_N * H_N * XP) return;
  int k = idx % XP; int r = idx / XP;
  o[idx] = f2bf(k < IN_N ? W1[(size_t)r * IN_N + k] : 0.f);
}
// A buffers in frag layout [z][mb 64][k8 68][mrow 32][e8 8]; A0 gets x_0, rest 0
__global__ void init_Afrag_k(u16* __restrict__ A0, u16* __restrict__ A1,
                             const u16* __restrict__ xb) {
  int idx = blockIdx.x * 256 + threadIdx.x;
  if (idx >= ER_N * B_N * KA) return;
  int e8 = idx & 7, mrow = (idx >> 3) & 31;
  int k8 = (idx >> 8) % KB8;
  int mb = ((idx >> 8) / KB8) & 63;
  int k = k8 * 8 + e8, m = mb * 32 + mrow;
  u16 v = 0;
  if (k >= H_N && k < H_N + F_N) v = xb[(size_t)m * XP + (k - H_N)];
  A0[idx] = v;
  A1[idx] = 0;
}
__global__ void zero_i_k(int* __restrict__ p, int n) {
  int i = blockIdx.x * 256 + threadIdx.x;
  if (i < n) p[i] = 0;
}

extern "C" void kernel_launch(void* const* d_in, const int* in_sizes, int n_in,
                              void* d_out, int out_size, void* d_ws, size_t ws_size,
                              hipStream_t stream) {
  const float* x   = (const float*)d_in[0];
  const float* Wg  = (const float*)d_in[1];
  const float* bg  = (const float*)d_in[2];
  const float* Wih = (const float*)d_in[3];
  const float* Whh = (const float*)d_in[4];
  const float* bih = (const float*)d_in[5];
  const float* bhh = (const float*)d_in[6];
  const float* fcW = (const float*)d_in[7];
  const float* fcb = (const float*)d_in[8];
  const float* W1  = (const float*)d_in[9];
  const float* b1  = (const float*)d_in[10];
  const float* W2  = (const float*)d_in[11];
  const float* b2  = (const float*)d_in[12];
  float* out = (float*)d_out;

  char* p = (char*)d_ws;
  auto take = [&](size_t bytes) { void* q = (void*)p; p += (bytes + 255) & ~(size_t)255; return q; };
  u16*   xb    = (u16*)  take((size_t)B_N * XP * 2);
  u16*   Wc    = (u16*)  take((size_t)ER_N * G4H * KA * 2);
  float* brec  = (float*)take((size_t)ER_N * G4H * 4);
  u16*   fcWb  = (u16*)  take((size_t)ER_N * OUT_N * H_N * 2);
  u16*   W1b   = (u16*)  take((size_t)ES_N * H_N * XP * 2);
  u16*   W2b   = (u16*)  take((size_t)ES_N * OUT_N * H_N * 2);
  u16*   A0    = (u16*)  take((size_t)ER_N * B_N * KA * 2);
  u16*   A1    = (u16*)  take((size_t)ER_N * B_N * KA * 2);
  u16*   Hlast = (u16*)  take((size_t)ER_N * B_N * H_N * 2);
  u16*   H1    = (u16*)  take((size_t)ES_N * B_N * H_N * 2);
  float* Ob    = (float*)take((size_t)E_N * B_N * OUT_N * 4);
  float* Wgt   = (float*)take((size_t)B_N * E_N * 4);
  int*   Gbar  = (int*)  take((size_t)16 * 64 * 4);   // 16 group counters, 256B apart

  dim3 blk(256);
  prep_x_k    <<<CDIV(B_N * XP, 256),           blk, 0, stream>>>(x, xb);
  prep_wfrag_k<<<CDIV(ER_N * G4H * KA, 256),    blk, 0, stream>>>(Whh, Wih, Wc);
  prep_bfrag_k<<<CDIV(ER_N * G4H, 256),         blk, 0, stream>>>(bih, bhh, brec);
  cvt_k       <<<CDIV(ER_N * OUT_N * H_N, 256), blk, 0, stream>>>(fcW, fcWb, ER_N * OUT_N * H_N);
  prep_w1_k   <<<CDIV(ES_N * H_N * XP, 256),    blk, 0, stream>>>(W1, W1b);
  cvt_k       <<<CDIV(ES_N * OUT_N * H_N, 256), blk, 0, stream>>>(W2, W2b, ES_N * OUT_N * H_N);
  init_Afrag_k<<<CDIV(ER_N * B_N * KA, 256),    blk, 0, stream>>>(A0, A1, xb);
  zero_i_k    <<<CDIV(16 * 64, 256),            blk, 0, stream>>>(Gbar, 16 * 64);
  gate_k      <<<B_N / 4,                       blk, 0, stream>>>(x, Wg, bg, Wgt);

  // ---- persistent LSTM: one cooperative launch, 27 group barriers ----
  constexpr unsigned ldsBytes = 4u * KB8 * 256u * 2u;   // 139264
  hipFuncSetAttribute((const void*)lstm_persist,
                      hipFuncAttributeMaxDynamicSharedMemorySize, ldsBytes);
  {
    const u16* a_Wc = Wc; const float* a_br = brec; const u16* a_xb = xb;
    u16* a_A0 = A0; u16* a_A1 = A1; u16* a_Hl = Hlast; int* a_gb = Gbar;
    void* args[] = {(void*)&a_Wc, (void*)&a_br, (void*)&a_xb,
                    (void*)&a_A0, (void*)&a_A1, (void*)&a_Hl, (void*)&a_gb};
    hipLaunchCooperativeKernel((const void*)lstm_persist, dim3(256), dim3(512),
                               args, ldsBytes, stream);
  }

  // ---- fc on h_last -> Ob[0..3] ----
  gemm_bt<0, 0><<<dim3(OUT_N / 128, B_N / 128, ER_N), blk, 0, stream>>>(
      Hlast, H_N, (long)B_N * H_N,
      fcWb, H_N, (long)OUT_N * H_N,
      fcb, OUT_N,
      (void*)Ob, OUT_N, (long)B_N * OUT_N, H_N);

  // ---- simple experts ----
  gemm_bt<1, 1><<<dim3(H_N / 128, B_N / 128, ES_N), blk, 0, stream>>>(
      xb, XP, 0L,
      W1b, XP, (long)H_N * XP,
      b1, H_N,
      (void*)H1, H_N, (long)B_N * H_N, XP);
  gemm_bt<0, 0><<<dim3(OUT_N / 128, B_N / 128, ES_N), blk, 0, stream>>>(
      H1, H_N, (long)B_N * H_N,
      W2b, H_N, (long)OUT_N * H_N,
      b2, OUT_N,
      (void*)(Ob + (size_t)ER_N * B_N * OUT_N), OUT_N, (long)B_N * OUT_N, H_N);

  combine_k<<<CDIV(B_N * OUT_N, 256), blk, 0, stream>>>(Ob, Wgt, out);
}

// Round 9
// 1109.975 us; speedup vs baseline: 1.0902x; 1.0902x over previous
//
#include <hip/hip_runtime.h>
#include <stdint.h>

#define CDIV(a,b) (((a)+(b)-1)/(b))

typedef unsigned short u16;
using bf16x8   = __attribute__((ext_vector_type(8))) short;
using floatx4  = __attribute__((ext_vector_type(4))) float;
using floatx16 = __attribute__((ext_vector_type(16))) float;

constexpr int B_N   = 2048;   // batch
constexpr int IN_N  = 784;
constexpr int H_N   = 512;
constexpr int OUT_N = 512;
constexpr int E_N   = 8;
constexpr int ER_N  = 4;      // recurrent experts
constexpr int ES_N  = 4;      // simple experts
constexpr int T_N   = 28;
constexpr int F_N   = 28;
constexpr int G4H   = 2048;   // 4*H
constexpr int KA    = 544;    // 512 (h) + 28 (x_t) + 4 pad
constexpr int KB8   = KA / 8; // 68 k8-blocks
constexpr int NKI   = KA / 16;// 34 mfma k-iters
constexpr int XP    = 800;    // 784 padded

__device__ __forceinline__ u16 f2bf(float f) {
  union { float f; uint32_t u; } v; v.f = f;
  uint32_t r = v.u + 0x7fffu + ((v.u >> 16) & 1u);   // RNE
  return (u16)(r >> 16);
}
__device__ __forceinline__ float sigm(float x)  { return 1.f / (1.f + __expf(-x)); }
__device__ __forceinline__ float tanhf_(float x){ return 1.f - 2.f / (__expf(2.f * x) + 1.f); }

__device__ __forceinline__ void async16(const void* g, void* l) {
  __builtin_amdgcn_global_load_lds(
      (__attribute__((address_space(1))) void*)g,
      (__attribute__((address_space(3))) void*)l, 16, 0, 0);
}

// ============ persistent weight-stationary LSTM, v6: cheap-release barrier ============
// 256 blocks x 512 threads (cooperative, 1 block/CU, 139 KB LDS).
// XCD swizzle: xcd=blk&7, i=blk>>3, nt=i&15, g=(i>>4)*8+xcd, z=g>>2, mr=g&3
//   -> the 16 blocks of group (z,mr) (producers AND consumers of the same
//      h rows) share one XCD; 2 groups per XCD.
// W slice (4 gate-tiles of 32 rows x KA) staged to LDS once; c in VGPRs all
// 28 steps. h/x stores are NONTEMPORAL (no dirty L2) so the group barrier's
// device-scope release has (almost) nothing to write back — the barrier
// reduces to waitcnt + LLC atomic + spin + L2-inv. Correct for any block->XCD
// mapping (stores drained + agent release/acquire), swizzle is speed-only.
__global__ __launch_bounds__(512, 2)
void lstm_persist(const u16* __restrict__ Wc, const float* __restrict__ brec,
                  const u16* __restrict__ xb, u16* __restrict__ A0,
                  u16* __restrict__ A1, u16* __restrict__ Hlast,
                  int* __restrict__ Gbar)
{
  extern __shared__ __align__(16) u16 Ws[];   // 4*KB8*256 u16 = 139264 B
  const int tid  = threadIdx.x;
  const int lane = tid & 63;
  const int wave = tid >> 6;
  const int blk  = blockIdx.x;
  const int xcd  = blk & 7;
  const int i8   = blk >> 3;
  const int nt   = i8 & 15;
  const int g    = (i8 >> 4) * 8 + xcd;       // group 0..15
  const int z    = g >> 2;
  const int mr   = g & 3;
  const int ln   = lane & 31;
  const int hw   = lane >> 5;
  const int gslot = g * 64;                   // 256B-spaced counter per group

  // ---- stage resident W slice into LDS (once): 17 x 1KB async chunks/wave ----
  {
    const u16* Wsrc = Wc + (size_t)(z * 16 + nt) * (4 * KB8 * 256);
    const int base = wave * (17 * 512);        // u16 units
#pragma unroll
    for (int it = 0; it < 17; ++it)
      async16(Wsrc + base + it * 512 + lane * 8, Ws + base + it * 512);
  }

  float bb[4];
#pragma unroll
  for (int j = 0; j < 4; ++j)
    bb[j] = brec[((z * 16 + nt) * 4 + j) * 32 + ln];

  float c[2][16];
#pragma unroll
  for (int i = 0; i < 2; ++i)
#pragma unroll
    for (int r = 0; r < 16; ++r) c[i][r] = 0.f;

  const int mblk0 = mr * 16 + wave * 2;
  const int hcol  = nt * 32 + ln;
  const size_t zoff = (size_t)z * ((size_t)64 * KB8 * 256);
  __syncthreads();   // W resident

  for (int t = 0; t < T_N; ++t) {
    const u16* Az  = ((t & 1) ? A1 : A0) + zoff;
    u16*       Aoz = ((t & 1) ? A0 : A1) + zoff;

    const u16* Ap0 = Az + ((size_t)mblk0 * KB8 + hw) * 256 + ln * 8;
    const u16* Ap1 = Az + ((size_t)(mblk0 + 1) * KB8 + hw) * 256 + ln * 8;

    bf16x8 pa0[2], pa1[2];                     // depth-2 A prefetch ring
    pa0[0] = *(const bf16x8*)Ap0;          pa1[0] = *(const bf16x8*)Ap1;
    pa0[1] = *(const bf16x8*)(Ap0 + 512);  pa1[1] = *(const bf16x8*)(Ap1 + 512);

    floatx16 acc[2][4] = {};
#pragma unroll 2
    for (int kk = 0; kk < NKI; ++kk) {
      bf16x8 a0 = pa0[kk & 1], a1 = pa1[kk & 1];
      if (kk + 2 < NKI) {
        pa0[kk & 1] = *(const bf16x8*)(Ap0 + (size_t)(kk + 2) * 512);
        pa1[kk & 1] = *(const bf16x8*)(Ap1 + (size_t)(kk + 2) * 512);
      }
      const u16* Bp = Ws + (2 * kk + hw) * 256 + ln * 8;
      bf16x8 b0 = *(const bf16x8*)(Bp);
      bf16x8 b1 = *(const bf16x8*)(Bp + 1 * KB8 * 256);
      bf16x8 b2 = *(const bf16x8*)(Bp + 2 * KB8 * 256);
      bf16x8 b3 = *(const bf16x8*)(Bp + 3 * KB8 * 256);
      acc[0][0] = __builtin_amdgcn_mfma_f32_32x32x16_bf16(a0, b0, acc[0][0], 0, 0, 0);
      acc[0][1] = __builtin_amdgcn_mfma_f32_32x32x16_bf16(a0, b1, acc[0][1], 0, 0, 0);
      acc[0][2] = __builtin_amdgcn_mfma_f32_32x32x16_bf16(a0, b2, acc[0][2], 0, 0, 0);
      acc[0][3] = __builtin_amdgcn_mfma_f32_32x32x16_bf16(a0, b3, acc[0][3], 0, 0, 0);
      acc[1][0] = __builtin_amdgcn_mfma_f32_32x32x16_bf16(a1, b0, acc[1][0], 0, 0, 0);
      acc[1][1] = __builtin_amdgcn_mfma_f32_32x32x16_bf16(a1, b1, acc[1][1], 0, 0, 0);
      acc[1][2] = __builtin_amdgcn_mfma_f32_32x32x16_bf16(a1, b2, acc[1][2], 0, 0, 0);
      acc[1][3] = __builtin_amdgcn_mfma_f32_32x32x16_bf16(a1, b3, acc[1][3], 0, 0, 0);
    }

    // ---- cell epilogue: c in registers; h stores NONTEMPORAL ----
    const int last = (t == T_N - 1);
#pragma unroll
    for (int i = 0; i < 2; ++i) {
      const int mb = mblk0 + i;
#pragma unroll
      for (int r = 0; r < 16; ++r) {
        float pi = acc[i][0][r] + bb[0];
        float pf = acc[i][1][r] + bb[1];
        float pg = acc[i][2][r] + bb[2];
        float po = acc[i][3][r] + bb[3];
        float cv = sigm(pf) * c[i][r] + sigm(pi) * tanhf_(pg);
        c[i][r] = cv;
        u16 hb = f2bf(sigm(po) * tanhf_(cv));
        // 32x32 C/D layout: col=lane&31, row=(r&3)+8*(r>>2)+4*(lane>>5)
        int mrow = 4 * hw + (r & 3) + 8 * (r >> 2);
        if (!last)
          __builtin_nontemporal_store(hb,
              &Aoz[((size_t)mb * KB8 + (hcol >> 3)) * 256 + mrow * 8 + (hcol & 7)]);
        else
          Hlast[((size_t)(z * B_N + mb * 32 + mrow)) * H_N + hcol] = hb;
      }
    }

    // ---- stage x_{t+1} (k in [512,540)) into Aout: spread over all 16 nt blocks ----
    if (t + 1 < T_N) {
      for (int idx = nt * 512 + tid; idx < 512 * F_N; idx += 16 * 512) {
        int ml  = idx / F_N, col = idx - ml * F_N;
        int m   = mr * 512 + ml;
        int k   = H_N + col;
        __builtin_nontemporal_store(xb[(size_t)m * XP + (t + 1) * F_N + col],
            &Aoz[((size_t)(m >> 5) * KB8 + (k >> 3)) * 256 + (m & 31) * 8 + (k & 7)]);
      }

      // ---- 16-block group barrier (z,mr): monotonic counter ----
      __syncthreads();   // drains vmcnt(0): all waves' nt-stores complete
      if (tid == 0) {
        __hip_atomic_fetch_add(&Gbar[gslot], 1, __ATOMIC_RELEASE,
                               __HIP_MEMORY_SCOPE_AGENT);
        const int target = 16 * (t + 1);
        while (__hip_atomic_load(&Gbar[gslot], __ATOMIC_RELAXED,
                                 __HIP_MEMORY_SCOPE_AGENT) < target)
          __builtin_amdgcn_s_sleep(1);
        __builtin_amdgcn_fence(__ATOMIC_ACQUIRE, "agent");
      }
      __syncthreads();
    }
  }
}

// ============ generic GEMM (tail): C[z] = A[z] @ B[z]^T + bias[z] ============
template<int RELU, int OBF>
__global__ __launch_bounds__(256, 2)
void gemm_bt(const u16* __restrict__ A, int lda, long sAz,
             const u16* __restrict__ Bw, int ldb, long sBz,
             const float* __restrict__ bias, int sBiz,
             void* __restrict__ Cv, int ldc, long sCz,
             int K)
{
  __shared__ __align__(16) u16 As[128 * 32];
  __shared__ __align__(16) u16 Bs[128 * 32];
  const int tid  = threadIdx.x;
  const int lane = tid & 63;
  const int wave = tid >> 6;
  const int m0 = blockIdx.y * 128;
  const int n0 = blockIdx.x * 128;
  const int z  = blockIdx.z;
  const u16* Ab = A  + (size_t)z * sAz;
  const u16* Bb = Bw + (size_t)z * sBz;

  const int wm   = (wave & 1) * 64;
  const int wn   = (wave >> 1) * 64;
  const int lm   = lane & 15;
  const int quad = lane >> 4;

  const int s0 = wave * 64 + lane;
  const int r0 = s0 >> 2, c0 = (s0 & 3) * 8;
  const int s1 = s0 + 256;
  const int r1 = s1 >> 2, c1 = (s1 & 3) * 8;

  floatx4 acc[4][4] = {};

  for (int k0 = 0; k0 < K; k0 += 32) {
    async16(Ab + (size_t)(m0 + r0) * lda + (k0 + c0), As + wave * 512);
    async16(Ab + (size_t)(m0 + r1) * lda + (k0 + c1), As + 2048 + wave * 512);
    async16(Bb + (size_t)(n0 + r0) * ldb + (k0 + c0), Bs + wave * 512);
    async16(Bb + (size_t)(n0 + r1) * ldb + (k0 + c1), Bs + 2048 + wave * 512);
    __syncthreads();
    bf16x8 af[4], bf_[4];
#pragma unroll
    for (int i = 0; i < 4; ++i)
      af[i] = *(const bf16x8*)&As[(wm + i * 16 + lm) * 32 + quad * 8];
#pragma unroll
    for (int j = 0; j < 4; ++j)
      bf_[j] = *(const bf16x8*)&Bs[(wn + j * 16 + lm) * 32 + quad * 8];
#pragma unroll
    for (int i = 0; i < 4; ++i)
#pragma unroll
      for (int j = 0; j < 4; ++j)
        acc[i][j] = __builtin_amdgcn_mfma_f32_16x16x32_bf16(af[i], bf_[j], acc[i][j], 0, 0, 0);
    __syncthreads();
  }

  float bj[4];
#pragma unroll
  for (int j = 0; j < 4; ++j)
    bj[j] = bias ? bias[z * sBiz + n0 + wn + j * 16 + lm] : 0.f;

#pragma unroll
  for (int i = 0; i < 4; ++i) {
#pragma unroll
    for (int r = 0; r < 4; ++r) {
      int m = m0 + wm + i * 16 + quad * 4 + r;
      size_t row = (size_t)z * sCz + (size_t)m * ldc;
#pragma unroll
      for (int j = 0; j < 4; ++j) {
        int n = n0 + wn + j * 16 + lm;
        float v = acc[i][j][r] + bj[j];
        if (RELU) v = fmaxf(v, 0.f);
        if (OBF) ((u16*)Cv)[row + n] = f2bf(v);
        else     ((float*)Cv)[row + n] = v;
      }
    }
  }
}

// ============ gate: softmax(scores/e), top-5, renormalize. one wave per row ============
__global__ __launch_bounds__(256)
void gate_k(const float* __restrict__ x, const float* __restrict__ Wg,
            const float* __restrict__ bg, float* __restrict__ Wt)
{
  int lane = threadIdx.x & 63;
  int row  = blockIdx.x * 4 + (threadIdx.x >> 6);
  float ps[E_N];
#pragma unroll
  for (int e = 0; e < E_N; ++e) ps[e] = 0.f;
  const float* xr = x + (size_t)row * IN_N;
  for (int k = lane; k < IN_N; k += 64) {
    float xv = xr[k];
#pragma unroll
    for (int e = 0; e < E_N; ++e) ps[e] += xv * Wg[e * IN_N + k];
  }
#pragma unroll
  for (int e = 0; e < E_N; ++e) {
#pragma unroll
    for (int off = 32; off >= 1; off >>= 1) ps[e] += __shfl_down(ps[e], off);
  }
  if (lane == 0) {
    float s[E_N], mx = -1e30f;
#pragma unroll
    for (int e = 0; e < E_N; ++e) { s[e] = (ps[e] + bg[e]) * 0.36787944117144233f; mx = fmaxf(mx, s[e]); }
    float pr[E_N], sum = 0.f;
#pragma unroll
    for (int e = 0; e < E_N; ++e) { pr[e] = __expf(s[e] - mx); sum += pr[e]; }
    float inv = 1.f / sum;
#pragma unroll
    for (int e = 0; e < E_N; ++e) pr[e] *= inv;
    unsigned used = 0; float wsum = 0.f;
    for (int k = 0; k < 5; ++k) {
      int am = -1; float bv = -1.f;
      for (int e = 0; e < E_N; ++e)
        if (!((used >> e) & 1) && pr[e] > bv) { bv = pr[e]; am = e; }
      used |= 1u << am; wsum += pr[am];
    }
    float winv = 1.f / (wsum + 1e-8f);
    for (int e = 0; e < E_N; ++e)
      Wt[row * E_N + e] = ((used >> e) & 1) ? pr[e] * winv : 0.f;
  }
}

// ============ combine ============
__global__ __launch_bounds__(256)
void combine_k(const float* __restrict__ O, const float* __restrict__ Wt, float* __restrict__ out)
{
  int idx = blockIdx.x * 256 + threadIdx.x;
  if (idx >= B_N * OUT_N) return;
  int b = idx / OUT_N;
  float a = 0.f;
#pragma unroll
  for (int e = 0; e < E_N; ++e)
    a += Wt[b * E_N + e] * O[(size_t)e * B_N * OUT_N + idx];
  out[idx] = a;
}

// ============ prep kernels ============
__global__ void prep_x_k(const float* __restrict__ x, u16* __restrict__ xb) {
  int idx = blockIdx.x * 256 + threadIdx.x;
  if (idx >= B_N * XP) return;
  int k = idx % XP, b = idx / XP;
  xb[idx] = f2bf(k < IN_N ? x[(size_t)b * IN_N + k] : 0.f);
}
// W in B-frag layout: [z][nt][gate j 4][k8][ln 32][e8 8]; gate j holds h = 32*nt + ln
__global__ void prep_wfrag_k(const float* __restrict__ Whh, const float* __restrict__ Wih,
                             u16* __restrict__ Wc) {
  int idx = blockIdx.x * 256 + threadIdx.x;
  if (idx >= ER_N * G4H * KA) return;
  int e8 = idx & 7, ln = (idx >> 3) & 31;
  int k8 = (idx >> 8) % KB8;
  int rest = (idx >> 8) / KB8;
  int j = rest & 3, nt = (rest >> 2) & 15, z = rest >> 6;
  int h = nt * 32 + ln, k = k8 * 8 + e8;
  int g = j * H_N + h;
  float v = 0.f;
  if (k < H_N)            v = Whh[((size_t)(z * G4H + g)) * H_N + k];
  else if (k < H_N + F_N) v = Wih[((size_t)(z * G4H + g)) * F_N + (k - H_N)];
  Wc[idx] = f2bf(v);
}
__global__ void prep_bfrag_k(const float* __restrict__ bih, const float* __restrict__ bhh,
                             float* __restrict__ o) {
  int idx = blockIdx.x * 256 + threadIdx.x;
  if (idx >= ER_N * G4H) return;
  int ln = idx & 31, j = (idx >> 5) & 3, nt = (idx >> 7) & 15, z = idx >> 11;
  int g = z * G4H + j * H_N + nt * 32 + ln;
  o[idx] = bih[g] + bhh[g];
}
__global__ void cvt_k(const float* __restrict__ in, u16* __restrict__ o, int n) {
  int idx = blockIdx.x * 256 + threadIdx.x;
  if (idx < n) o[idx] = f2bf(in[idx]);
}
__global__ void prep_w1_k(const float* __restrict__ W1, u16* __restrict__ o) {
  int idx = blockIdx.x * 256 + threadIdx.x;
  if (idx >= ES_N * H_N * XP) return;
  int k = idx % XP; int r = idx / XP;
  o[idx] = f2bf(k < IN_N ? W1[(size_t)r * IN_N + k] : 0.f);
}
// A buffers in frag layout [z][mb 64][k8 68][mrow 32][e8 8]; A0 gets x_0, rest 0
__global__ void init_Afrag_k(u16* __restrict__ A0, u16* __restrict__ A1,
                             const u16* __restrict__ xb) {
  int idx = blockIdx.x * 256 + threadIdx.x;
  if (idx >= ER_N * B_N * KA) return;
  int e8 = idx & 7, mrow = (idx >> 3) & 31;
  int k8 = (idx >> 8) % KB8;
  int mb = ((idx >> 8) / KB8) & 63;
  int k = k8 * 8 + e8, m = mb * 32 + mrow;
  u16 v = 0;
  if (k >= H_N && k < H_N + F_N) v = xb[(size_t)m * XP + (k - H_N)];
  A0[idx] = v;
  A1[idx] = 0;
}
__global__ void zero_i_k(int* __restrict__ p, int n) {
  int i = blockIdx.x * 256 + threadIdx.x;
  if (i < n) p[i] = 0;
}

extern "C" void kernel_launch(void* const* d_in, const int* in_sizes, int n_in,
                              void* d_out, int out_size, void* d_ws, size_t ws_size,
                              hipStream_t stream) {
  const float* x   = (const float*)d_in[0];
  const float* Wg  = (const float*)d_in[1];
  const float* bg  = (const float*)d_in[2];
  const float* Wih = (const float*)d_in[3];
  const float* Whh = (const float*)d_in[4];
  const float* bih = (const float*)d_in[5];
  const float* bhh = (const float*)d_in[6];
  const float* fcW = (const float*)d_in[7];
  const float* fcb = (const float*)d_in[8];
  const float* W1  = (const float*)d_in[9];
  const float* b1  = (const float*)d_in[10];
  const float* W2  = (const float*)d_in[11];
  const float* b2  = (const float*)d_in[12];
  float* out = (float*)d_out;

  char* p = (char*)d_ws;
  auto take = [&](size_t bytes) { void* q = (void*)p; p += (bytes + 255) & ~(size_t)255; return q; };
  u16*   xb    = (u16*)  take((size_t)B_N * XP * 2);
  u16*   Wc    = (u16*)  take((size_t)ER_N * G4H * KA * 2);
  float* brec  = (float*)take((size_t)ER_N * G4H * 4);
  u16*   fcWb  = (u16*)  take((size_t)ER_N * OUT_N * H_N * 2);
  u16*   W1b   = (u16*)  take((size_t)ES_N * H_N * XP * 2);
  u16*   W2b   = (u16*)  take((size_t)ES_N * OUT_N * H_N * 2);
  u16*   A0    = (u16*)  take((size_t)ER_N * B_N * KA * 2);
  u16*   A1    = (u16*)  take((size_t)ER_N * B_N * KA * 2);
  u16*   Hlast = (u16*)  take((size_t)ER_N * B_N * H_N * 2);
  u16*   H1    = (u16*)  take((size_t)ES_N * B_N * H_N * 2);
  float* Ob    = (float*)take((size_t)E_N * B_N * OUT_N * 4);
  float* Wgt   = (float*)take((size_t)B_N * E_N * 4);
  int*   Gbar  = (int*)  take((size_t)16 * 64 * 4);   // 16 group counters, 256B apart

  dim3 blk(256);
  prep_x_k    <<<CDIV(B_N * XP, 256),           blk, 0, stream>>>(x, xb);
  prep_wfrag_k<<<CDIV(ER_N * G4H * KA, 256),    blk, 0, stream>>>(Whh, Wih, Wc);
  prep_bfrag_k<<<CDIV(ER_N * G4H, 256),         blk, 0, stream>>>(bih, bhh, brec);
  cvt_k       <<<CDIV(ER_N * OUT_N * H_N, 256), blk, 0, stream>>>(fcW, fcWb, ER_N * OUT_N * H_N);
  prep_w1_k   <<<CDIV(ES_N * H_N * XP, 256),    blk, 0, stream>>>(W1, W1b);
  cvt_k       <<<CDIV(ES_N * OUT_N * H_N, 256), blk, 0, stream>>>(W2, W2b, ES_N * OUT_N * H_N);
  init_Afrag_k<<<CDIV(ER_N * B_N * KA, 256),    blk, 0, stream>>>(A0, A1, xb);
  zero_i_k    <<<CDIV(16 * 64, 256),            blk, 0, stream>>>(Gbar, 16 * 64);
  gate_k      <<<B_N / 4,                       blk, 0, stream>>>(x, Wg, bg, Wgt);

  // ---- persistent LSTM: one cooperative launch, 27 group barriers ----
  constexpr unsigned ldsBytes = 4u * KB8 * 256u * 2u;   // 139264
  hipFuncSetAttribute((const void*)lstm_persist,
                      hipFuncAttributeMaxDynamicSharedMemorySize, ldsBytes);
  {
    const u16* a_Wc = Wc; const float* a_br = brec; const u16* a_xb = xb;
    u16* a_A0 = A0; u16* a_A1 = A1; u16* a_Hl = Hlast; int* a_gb = Gbar;
    void* args[] = {(void*)&a_Wc, (void*)&a_br, (void*)&a_xb,
                    (void*)&a_A0, (void*)&a_A1, (void*)&a_Hl, (void*)&a_gb};
    hipLaunchCooperativeKernel((const void*)lstm_persist, dim3(256), dim3(512),
                               args, ldsBytes, stream);
  }

  // ---- fc on h_last -> Ob[0..3] ----
  gemm_bt<0, 0><<<dim3(OUT_N / 128, B_N / 128, ER_N), blk, 0, stream>>>(
      Hlast, H_N, (long)B_N * H_N,
      fcWb, H_N, (long)OUT_N * H_N,
      fcb, OUT_N,
      (void*)Ob, OUT_N, (long)B_N * OUT_N, H_N);

  // ---- simple experts ----
  gemm_bt<1, 1><<<dim3(H_N / 128, B_N / 128, ES_N), blk, 0, stream>>>(
      xb, XP, 0L,
      W1b, XP, (long)H_N * XP,
      b1, H_N,
      (void*)H1, H_N, (long)B_N * H_N, XP);
  gemm_bt<0, 0><<<dim3(OUT_N / 128, B_N / 128, ES_N), blk, 0, stream>>>(
      H1, H_N, (long)B_N * H_N,
      W2b, H_N, (long)OUT_N * H_N,
      b2, OUT_N,
      (void*)(Ob + (size_t)ER_N * B_N * OUT_N), OUT_N, (long)B_N * OUT_N, H_N);

  combine_k<<<CDIV(B_N * OUT_N, 256), blk, 0, stream>>>(Ob, Wgt, out);
}

// Round 10
// 941.153 us; speedup vs baseline: 1.2858x; 1.1794x over previous
//
#include <hip/hip_runtime.h>
#include <stdint.h>

#define CDIV(a,b) (((a)+(b)-1)/(b))

typedef unsigned short u16;
using bf16x8   = __attribute__((ext_vector_type(8))) short;
using floatx4  = __attribute__((ext_vector_type(4))) float;
using floatx16 = __attribute__((ext_vector_type(16))) float;

constexpr int B_N   = 2048;   // batch
constexpr int IN_N  = 784;
constexpr int H_N   = 512;
constexpr int OUT_N = 512;
constexpr int E_N   = 8;
constexpr int ER_N  = 4;      // recurrent experts
constexpr int ES_N  = 4;      // simple experts
constexpr int T_N   = 28;
constexpr int F_N   = 28;
constexpr int G4H   = 2048;   // 4*H
constexpr int KA    = 544;    // 512 (h) + 28 (x_t) + 4 pad
constexpr int KB8   = KA / 8; // 68 k8-blocks
constexpr int NKI   = KA / 16;// 34 mfma k-iters
constexpr int XP    = 800;    // 784 padded

__device__ __forceinline__ u16 f2bf(float f) {
  union { float f; uint32_t u; } v; v.f = f;
  uint32_t r = v.u + 0x7fffu + ((v.u >> 16) & 1u);   // RNE
  return (u16)(r >> 16);
}
// fast activations: v_rcp_f32 (~1 ulp) instead of IEEE divide sequences
__device__ __forceinline__ float sigm(float x) {
  return __builtin_amdgcn_rcpf(1.f + __expf(-x));
}
__device__ __forceinline__ float tanhf_(float x) {
  return __builtin_fmaf(-2.f, __builtin_amdgcn_rcpf(__expf(2.f * x) + 1.f), 1.f);
}

__device__ __forceinline__ void async16(const void* g, void* l) {
  __builtin_amdgcn_global_load_lds(
      (__attribute__((address_space(1))) void*)g,
      (__attribute__((address_space(3))) void*)l, 16, 0, 0);
}

// ============ persistent weight-stationary LSTM, v7: lean-VALU epilogue ============
// 256 blocks x 512 threads (cooperative, 1 block/CU, 139 KB LDS).
// XCD swizzle: xcd=blk&7, i=blk>>3, nt=i&15, g=(i>>4)*8+xcd, z=g>>2, mr=g&3
//   -> the 16 blocks of group (z,mr) share one XCD (speed-only heuristic).
// W slice staged to LDS once; c in VGPRs all 28 steps; bias folded into the
// MFMA accumulator init; h/x stores nontemporal (no dirty L2 -> cheap release).
// Per step: A-frag loads -> 34x8 MFMA -> rcp-based cell epilogue -> NT h/x
// stores -> 16-block monotonic-counter barrier (release add / relaxed spin /
// acquire fence). Correct for any block->XCD mapping (G16).
__global__ __launch_bounds__(512, 2)
void lstm_persist(const u16* __restrict__ Wc, const float* __restrict__ brec,
                  const u16* __restrict__ xb, u16* __restrict__ A0,
                  u16* __restrict__ A1, u16* __restrict__ Hlast,
                  int* __restrict__ Gbar)
{
  extern __shared__ __align__(16) u16 Ws[];   // 4*KB8*256 u16 = 139264 B
  const int tid  = threadIdx.x;
  const int lane = tid & 63;
  const int wave = tid >> 6;
  const int blk  = blockIdx.x;
  const int xcd  = blk & 7;
  const int i8   = blk >> 3;
  const int nt   = i8 & 15;
  const int g    = (i8 >> 4) * 8 + xcd;       // group 0..15
  const int z    = g >> 2;
  const int mr   = g & 3;
  const int ln   = lane & 31;
  const int hw   = lane >> 5;
  const int gslot = g * 64;                   // 256B-spaced counter per group

  // ---- stage resident W slice into LDS (once): 17 x 1KB async chunks/wave ----
  {
    const u16* Wsrc = Wc + (size_t)(z * 16 + nt) * (4 * KB8 * 256);
    const int base = wave * (17 * 512);        // u16 units
#pragma unroll
    for (int it = 0; it < 17; ++it)
      async16(Wsrc + base + it * 512 + lane * 8, Ws + base + it * 512);
  }

  float bb[4];
#pragma unroll
  for (int j = 0; j < 4; ++j)
    bb[j] = brec[((z * 16 + nt) * 4 + j) * 32 + ln];

  float c[2][16];
#pragma unroll
  for (int i = 0; i < 2; ++i)
#pragma unroll
    for (int r = 0; r < 16; ++r) c[i][r] = 0.f;

  const int mblk0 = mr * 16 + wave * 2;
  const int hcol  = nt * 32 + ln;
  const size_t zoff = (size_t)z * ((size_t)64 * KB8 * 256);
  __syncthreads();   // W resident

  for (int t = 0; t < T_N; ++t) {
    const u16* Az  = ((t & 1) ? A1 : A0) + zoff;
    u16*       Aoz = ((t & 1) ? A0 : A1) + zoff;

    const u16* Ap0 = Az + ((size_t)mblk0 * KB8 + hw) * 256 + ln * 8;
    const u16* Ap1 = Az + ((size_t)(mblk0 + 1) * KB8 + hw) * 256 + ln * 8;

    bf16x8 pa0[2], pa1[2];                     // depth-2 A prefetch ring
    pa0[0] = *(const bf16x8*)Ap0;          pa1[0] = *(const bf16x8*)Ap1;
    pa0[1] = *(const bf16x8*)(Ap0 + 512);  pa1[1] = *(const bf16x8*)(Ap1 + 512);

    // bias folded into accumulator init (C/D bias is column-only, r-invariant)
    floatx16 acc[2][4];
#pragma unroll
    for (int i = 0; i < 2; ++i)
#pragma unroll
      for (int j = 0; j < 4; ++j)
#pragma unroll
        for (int r = 0; r < 16; ++r)
          acc[i][j][r] = bb[j];

#pragma unroll 2
    for (int kk = 0; kk < NKI; ++kk) {
      bf16x8 a0 = pa0[kk & 1], a1 = pa1[kk & 1];
      if (kk + 2 < NKI) {
        pa0[kk & 1] = *(const bf16x8*)(Ap0 + (size_t)(kk + 2) * 512);
        pa1[kk & 1] = *(const bf16x8*)(Ap1 + (size_t)(kk + 2) * 512);
      }
      const u16* Bp = Ws + (2 * kk + hw) * 256 + ln * 8;
      bf16x8 b0 = *(const bf16x8*)(Bp);
      bf16x8 b1 = *(const bf16x8*)(Bp + 1 * KB8 * 256);
      bf16x8 b2 = *(const bf16x8*)(Bp + 2 * KB8 * 256);
      bf16x8 b3 = *(const bf16x8*)(Bp + 3 * KB8 * 256);
      acc[0][0] = __builtin_amdgcn_mfma_f32_32x32x16_bf16(a0, b0, acc[0][0], 0, 0, 0);
      acc[0][1] = __builtin_amdgcn_mfma_f32_32x32x16_bf16(a0, b1, acc[0][1], 0, 0, 0);
      acc[0][2] = __builtin_amdgcn_mfma_f32_32x32x16_bf16(a0, b2, acc[0][2], 0, 0, 0);
      acc[0][3] = __builtin_amdgcn_mfma_f32_32x32x16_bf16(a0, b3, acc[0][3], 0, 0, 0);
      acc[1][0] = __builtin_amdgcn_mfma_f32_32x32x16_bf16(a1, b0, acc[1][0], 0, 0, 0);
      acc[1][1] = __builtin_amdgcn_mfma_f32_32x32x16_bf16(a1, b1, acc[1][1], 0, 0, 0);
      acc[1][2] = __builtin_amdgcn_mfma_f32_32x32x16_bf16(a1, b2, acc[1][2], 0, 0, 0);
      acc[1][3] = __builtin_amdgcn_mfma_f32_32x32x16_bf16(a1, b3, acc[1][3], 0, 0, 0);
    }

    // ---- cell epilogue: rcp-based activations, c in registers, NT h stores ----
    const int last = (t == T_N - 1);
#pragma unroll
    for (int i = 0; i < 2; ++i) {
      const int mb = mblk0 + i;
#pragma unroll
      for (int r = 0; r < 16; ++r) {
        float cv = sigm(acc[i][1][r]) * c[i][r]
                 + sigm(acc[i][0][r]) * tanhf_(acc[i][2][r]);
        c[i][r] = cv;
        u16 hb = f2bf(sigm(acc[i][3][r]) * tanhf_(cv));
        // 32x32 C/D layout: col=lane&31, row=(r&3)+8*(r>>2)+4*(lane>>5)
        int mrow = 4 * hw + (r & 3) + 8 * (r >> 2);
        if (!last)
          __builtin_nontemporal_store(hb,
              &Aoz[((size_t)mb * KB8 + (hcol >> 3)) * 256 + mrow * 8 + (hcol & 7)]);
        else
          Hlast[((size_t)(z * B_N + mb * 32 + mrow)) * H_N + hcol] = hb;
      }
    }

    // ---- stage x_{t+1} (k in [512,540)) into Aout: spread over all 16 nt blocks ----
    if (t + 1 < T_N) {
      for (int idx = nt * 512 + tid; idx < 512 * F_N; idx += 16 * 512) {
        int ml  = idx / F_N, col = idx - ml * F_N;
        int m   = mr * 512 + ml;
        int k   = H_N + col;
        __builtin_nontemporal_store(xb[(size_t)m * XP + (t + 1) * F_N + col],
            &Aoz[((size_t)(m >> 5) * KB8 + (k >> 3)) * 256 + (m & 31) * 8 + (k & 7)]);
      }

      // ---- 16-block group barrier (z,mr): monotonic counter ----
      __syncthreads();   // drains vmcnt(0): all waves' nt-stores complete
      if (tid == 0) {
        __hip_atomic_fetch_add(&Gbar[gslot], 1, __ATOMIC_RELEASE,
                               __HIP_MEMORY_SCOPE_AGENT);
        const int target = 16 * (t + 1);
        while (__hip_atomic_load(&Gbar[gslot], __ATOMIC_RELAXED,
                                 __HIP_MEMORY_SCOPE_AGENT) < target)
          __builtin_amdgcn_s_sleep(1);
        __builtin_amdgcn_fence(__ATOMIC_ACQUIRE, "agent");
      }
      __syncthreads();
    }
  }
}

// ============ generic GEMM (tail): C[z] = A[z] @ B[z]^T + bias[z] ============
template<int RELU, int OBF>
__global__ __launch_bounds__(256, 2)
void gemm_bt(const u16* __restrict__ A, int lda, long sAz,
             const u16* __restrict__ Bw, int ldb, long sBz,
             const float* __restrict__ bias, int sBiz,
             void* __restrict__ Cv, int ldc, long sCz,
             int K)
{
  __shared__ __align__(16) u16 As[128 * 32];
  __shared__ __align__(16) u16 Bs[128 * 32];
  const int tid  = threadIdx.x;
  const int lane = tid & 63;
  const int wave = tid >> 6;
  const int m0 = blockIdx.y * 128;
  const int n0 = blockIdx.x * 128;
  const int z  = blockIdx.z;
  const u16* Ab = A  + (size_t)z * sAz;
  const u16* Bb = Bw + (size_t)z * sBz;

  const int wm   = (wave & 1) * 64;
  const int wn   = (wave >> 1) * 64;
  const int lm   = lane & 15;
  const int quad = lane >> 4;

  const int s0 = wave * 64 + lane;
  const int r0 = s0 >> 2, c0 = (s0 & 3) * 8;
  const int s1 = s0 + 256;
  const int r1 = s1 >> 2, c1 = (s1 & 3) * 8;

  floatx4 acc[4][4] = {};

  for (int k0 = 0; k0 < K; k0 += 32) {
    async16(Ab + (size_t)(m0 + r0) * lda + (k0 + c0), As + wave * 512);
    async16(Ab + (size_t)(m0 + r1) * lda + (k0 + c1), As + 2048 + wave * 512);
    async16(Bb + (size_t)(n0 + r0) * ldb + (k0 + c0), Bs + wave * 512);
    async16(Bb + (size_t)(n0 + r1) * ldb + (k0 + c1), Bs + 2048 + wave * 512);
    __syncthreads();
    bf16x8 af[4], bf_[4];
#pragma unroll
    for (int i = 0; i < 4; ++i)
      af[i] = *(const bf16x8*)&As[(wm + i * 16 + lm) * 32 + quad * 8];
#pragma unroll
    for (int j = 0; j < 4; ++j)
      bf_[j] = *(const bf16x8*)&Bs[(wn + j * 16 + lm) * 32 + quad * 8];
#pragma unroll
    for (int i = 0; i < 4; ++i)
#pragma unroll
      for (int j = 0; j < 4; ++j)
        acc[i][j] = __builtin_amdgcn_mfma_f32_16x16x32_bf16(af[i], bf_[j], acc[i][j], 0, 0, 0);
    __syncthreads();
  }

  float bj[4];
#pragma unroll
  for (int j = 0; j < 4; ++j)
    bj[j] = bias ? bias[z * sBiz + n0 + wn + j * 16 + lm] : 0.f;

#pragma unroll
  for (int i = 0; i < 4; ++i) {
#pragma unroll
    for (int r = 0; r < 4; ++r) {
      int m = m0 + wm + i * 16 + quad * 4 + r;
      size_t row = (size_t)z * sCz + (size_t)m * ldc;
#pragma unroll
      for (int j = 0; j < 4; ++j) {
        int n = n0 + wn + j * 16 + lm;
        float v = acc[i][j][r] + bj[j];
        if (RELU) v = fmaxf(v, 0.f);
        if (OBF) ((u16*)Cv)[row + n] = f2bf(v);
        else     ((float*)Cv)[row + n] = v;
      }
    }
  }
}

// ============ gate: softmax(scores/e), top-5, renormalize. one wave per row ============
__global__ __launch_bounds__(256)
void gate_k(const float* __restrict__ x, const float* __restrict__ Wg,
            const float* __restrict__ bg, float* __restrict__ Wt)
{
  int lane = threadIdx.x & 63;
  int row  = blockIdx.x * 4 + (threadIdx.x >> 6);
  float ps[E_N];
#pragma unroll
  for (int e = 0; e < E_N; ++e) ps[e] = 0.f;
  const float* xr = x + (size_t)row * IN_N;
  for (int k = lane; k < IN_N; k += 64) {
    float xv = xr[k];
#pragma unroll
    for (int e = 0; e < E_N; ++e) ps[e] += xv * Wg[e * IN_N + k];
  }
#pragma unroll
  for (int e = 0; e < E_N; ++e) {
#pragma unroll
    for (int off = 32; off >= 1; off >>= 1) ps[e] += __shfl_down(ps[e], off);
  }
  if (lane == 0) {
    float s[E_N], mx = -1e30f;
#pragma unroll
    for (int e = 0; e < E_N; ++e) { s[e] = (ps[e] + bg[e]) * 0.36787944117144233f; mx = fmaxf(mx, s[e]); }
    float pr[E_N], sum = 0.f;
#pragma unroll
    for (int e = 0; e < E_N; ++e) { pr[e] = __expf(s[e] - mx); sum += pr[e]; }
    float inv = 1.f / sum;
#pragma unroll
    for (int e = 0; e < E_N; ++e) pr[e] *= inv;
    unsigned used = 0; float wsum = 0.f;
    for (int k = 0; k < 5; ++k) {
      int am = -1; float bv = -1.f;
      for (int e = 0; e < E_N; ++e)
        if (!((used >> e) & 1) && pr[e] > bv) { bv = pr[e]; am = e; }
      used |= 1u << am; wsum += pr[am];
    }
    float winv = 1.f / (wsum + 1e-8f);
    for (int e = 0; e < E_N; ++e)
      Wt[row * E_N + e] = ((used >> e) & 1) ? pr[e] * winv : 0.f;
  }
}

// ============ combine ============
__global__ __launch_bounds__(256)
void combine_k(const float* __restrict__ O, const float* __restrict__ Wt, float* __restrict__ out)
{
  int idx = blockIdx.x * 256 + threadIdx.x;
  if (idx >= B_N * OUT_N) return;
  int b = idx / OUT_N;
  float a = 0.f;
#pragma unroll
  for (int e = 0; e < E_N; ++e)
    a += Wt[b * E_N + e] * O[(size_t)e * B_N * OUT_N + idx];
  out[idx] = a;
}

// ============ prep kernels ============
__global__ void prep_x_k(const float* __restrict__ x, u16* __restrict__ xb) {
  int idx = blockIdx.x * 256 + threadIdx.x;
  if (idx >= B_N * XP) return;
  int k = idx % XP, b = idx / XP;
  xb[idx] = f2bf(k < IN_N ? x[(size_t)b * IN_N + k] : 0.f);
}
// W in B-frag layout: [z][nt][gate j 4][k8][ln 32][e8 8]; gate j holds h = 32*nt + ln
__global__ void prep_wfrag_k(const float* __restrict__ Whh, const float* __restrict__ Wih,
                             u16* __restrict__ Wc) {
  int idx = blockIdx.x * 256 + threadIdx.x;
  if (idx >= ER_N * G4H * KA) return;
  int e8 = idx & 7, ln = (idx >> 3) & 31;
  int k8 = (idx >> 8) % KB8;
  int rest = (idx >> 8) / KB8;
  int j = rest & 3, nt = (rest >> 2) & 15, z = rest >> 6;
  int h = nt * 32 + ln, k = k8 * 8 + e8;
  int g = j * H_N + h;
  float v = 0.f;
  if (k < H_N)            v = Whh[((size_t)(z * G4H + g)) * H_N + k];
  else if (k < H_N + F_N) v = Wih[((size_t)(z * G4H + g)) * F_N + (k - H_N)];
  Wc[idx] = f2bf(v);
}
__global__ void prep_bfrag_k(const float* __restrict__ bih, const float* __restrict__ bhh,
                             float* __restrict__ o) {
  int idx = blockIdx.x * 256 + threadIdx.x;
  if (idx >= ER_N * G4H) return;
  int ln = idx & 31, j = (idx >> 5) & 3, nt = (idx >> 7) & 15, z = idx >> 11;
  int g = z * G4H + j * H_N + nt * 32 + ln;
  o[idx] = bih[g] + bhh[g];
}
__global__ void cvt_k(const float* __restrict__ in, u16* __restrict__ o, int n) {
  int idx = blockIdx.x * 256 + threadIdx.x;
  if (idx < n) o[idx] = f2bf(in[idx]);
}
__global__ void prep_w1_k(const float* __restrict__ W1, u16* __restrict__ o) {
  int idx = blockIdx.x * 256 + threadIdx.x;
  if (idx >= ES_N * H_N * XP) return;
  int k = idx % XP; int r = idx / XP;
  o[idx] = f2bf(k < IN_N ? W1[(size_t)r * IN_N + k] : 0.f);
}
// A buffers in frag layout [z][mb 64][k8 68][mrow 32][e8 8]; A0 gets x_0, rest 0
__global__ void init_Afrag_k(u16* __restrict__ A0, u16* __restrict__ A1,
                             const u16* __restrict__ xb) {
  int idx = blockIdx.x * 256 + threadIdx.x;
  if (idx >= ER_N * B_N * KA) return;
  int e8 = idx & 7, mrow = (idx >> 3) & 31;
  int k8 = (idx >> 8) % KB8;
  int mb = ((idx >> 8) / KB8) & 63;
  int k = k8 * 8 + e8, m = mb * 32 + mrow;
  u16 v = 0;
  if (k >= H_N && k < H_N + F_N) v = xb[(size_t)m * XP + (k - H_N)];
  A0[idx] = v;
  A1[idx] = 0;
}
__global__ void zero_i_k(int* __restrict__ p, int n) {
  int i = blockIdx.x * 256 + threadIdx.x;
  if (i < n) p[i] = 0;
}

extern "C" void kernel_launch(void* const* d_in, const int* in_sizes, int n_in,
                              void* d_out, int out_size, void* d_ws, size_t ws_size,
                              hipStream_t stream) {
  const float* x   = (const float*)d_in[0];
  const float* Wg  = (const float*)d_in[1];
  const float* bg  = (const float*)d_in[2];
  const float* Wih = (const float*)d_in[3];
  const float* Whh = (const float*)d_in[4];
  const float* bih = (const float*)d_in[5];
  const float* bhh = (const float*)d_in[6];
  const float* fcW = (const float*)d_in[7];
  const float* fcb = (const float*)d_in[8];
  const float* W1  = (const float*)d_in[9];
  const float* b1  = (const float*)d_in[10];
  const float* W2  = (const float*)d_in[11];
  const float* b2  = (const float*)d_in[12];
  float* out = (float*)d_out;

  char* p = (char*)d_ws;
  auto take = [&](size_t bytes) { void* q = (void*)p; p += (bytes + 255) & ~(size_t)255; return q; };
  u16*   xb    = (u16*)  take((size_t)B_N * XP * 2);
  u16*   Wc    = (u16*)  take((size_t)ER_N * G4H * KA * 2);
  float* brec  = (float*)take((size_t)ER_N * G4H * 4);
  u16*   Wcomb = (u16*)  take((size_t)E_N * OUT_N * H_N * 2);   // [fcW(4) | W2(4)] bf16
  u16*   W1b   = (u16*)  take((size_t)ES_N * H_N * XP * 2);
  u16*   A0    = (u16*)  take((size_t)ER_N * B_N * KA * 2);
  u16*   A1    = (u16*)  take((size_t)ER_N * B_N * KA * 2);
  u16*   Hcomb = (u16*)  take((size_t)E_N * B_N * H_N * 2);     // [Hlast(4) | H1(4)]
  float* bcomb = (float*)take((size_t)E_N * OUT_N * 4);         // [fcb(4) | b2(4)]
  float* Ob    = (float*)take((size_t)E_N * B_N * OUT_N * 4);
  float* Wgt   = (float*)take((size_t)B_N * E_N * 4);
  int*   Gbar  = (int*)  take((size_t)16 * 64 * 4);   // 16 group counters, 256B apart

  u16* Hlast = Hcomb;
  u16* H1    = Hcomb + (size_t)ER_N * B_N * H_N;

  dim3 blk(256);
  prep_x_k    <<<CDIV(B_N * XP, 256),           blk, 0, stream>>>(x, xb);
  prep_wfrag_k<<<CDIV(ER_N * G4H * KA, 256),    blk, 0, stream>>>(Whh, Wih, Wc);
  prep_bfrag_k<<<CDIV(ER_N * G4H, 256),         blk, 0, stream>>>(bih, bhh, brec);
  cvt_k       <<<CDIV(ER_N * OUT_N * H_N, 256), blk, 0, stream>>>(fcW, Wcomb, ER_N * OUT_N * H_N);
  cvt_k       <<<CDIV(ES_N * OUT_N * H_N, 256), blk, 0, stream>>>(
      W2, Wcomb + (size_t)ER_N * OUT_N * H_N, ES_N * OUT_N * H_N);
  prep_w1_k   <<<CDIV(ES_N * H_N * XP, 256),    blk, 0, stream>>>(W1, W1b);
  init_Afrag_k<<<CDIV(ER_N * B_N * KA, 256),    blk, 0, stream>>>(A0, A1, xb);
  zero_i_k    <<<CDIV(16 * 64, 256),            blk, 0, stream>>>(Gbar, 16 * 64);
  gate_k      <<<B_N / 4,                       blk, 0, stream>>>(x, Wg, bg, Wgt);
  hipMemcpyAsync(bcomb, fcb, (size_t)ER_N * OUT_N * 4,
                 hipMemcpyDeviceToDevice, stream);
  hipMemcpyAsync(bcomb + (size_t)ER_N * OUT_N, b2, (size_t)ES_N * OUT_N * 4,
                 hipMemcpyDeviceToDevice, stream);

  // ---- simple experts layer 1 (independent of LSTM) ----
  gemm_bt<1, 1><<<dim3(H_N / 128, B_N / 128, ES_N), blk, 0, stream>>>(
      xb, XP, 0L,
      W1b, XP, (long)H_N * XP,
      b1, H_N,
      (void*)H1, H_N, (long)B_N * H_N, XP);

  // ---- persistent LSTM: one cooperative launch, 27 group barriers ----
  constexpr unsigned ldsBytes = 4u * KB8 * 256u * 2u;   // 139264
  hipFuncSetAttribute((const void*)lstm_persist,
                      hipFuncAttributeMaxDynamicSharedMemorySize, ldsBytes);
  {
    const u16* a_Wc = Wc; const float* a_br = brec; const u16* a_xb = xb;
    u16* a_A0 = A0; u16* a_A1 = A1; u16* a_Hl = Hlast; int* a_gb = Gbar;
    void* args[] = {(void*)&a_Wc, (void*)&a_br, (void*)&a_xb,
                    (void*)&a_A0, (void*)&a_A1, (void*)&a_Hl, (void*)&a_gb};
    hipLaunchCooperativeKernel((const void*)lstm_persist, dim3(256), dim3(512),
                               args, ldsBytes, stream);
  }

  // ---- merged tail GEMM: z=0..3 fc(Hlast), z=4..7 simple layer 2 (H1) ----
  gemm_bt<0, 0><<<dim3(OUT_N / 128, B_N / 128, E_N), blk, 0, stream>>>(
      Hcomb, H_N, (long)B_N * H_N,
      Wcomb, H_N, (long)OUT_N * H_N,
      bcomb, OUT_N,
      (void*)Ob, OUT_N, (long)B_N * OUT_N, H_N);

  combine_k<<<CDIV(B_N * OUT_N, 256), blk, 0, stream>>>(Ob, Wgt, out);
}